// Round 12
// baseline (183.332 us; speedup 1.0000x reference)
//
#include <hip/hip_runtime.h>
#include <stdint.h>
#include <stddef.h>

// RadialCTC: cosine logits (norm_scale=32) -> log_softmax -> CTC(sum).
// Strategy: never materialize the (16384 x 1296) logits. GEMM (f16 MFMA)
// computes per-row sum(exp(logit)) fused in the epilogue; label log-probs via
// small f16 MFMA gather-GEMM; CTC alpha recursion one wave per sample.
// R9: linear f64 + pow2 renorm ctc. R11: XOR channel-slot LDS swizzle (gemm).
// R14: log2(sumexp) factored out (Msum). R15 FAILED: acquire-spin L2 storms.
// R18 (154.2): fused 2-step fwd chain: mega 54.9. R19 (153.2): XCD remap;
//   mega 54.4, VGPR 76 (set by gemm acc[4][4]).
// R20-R22: fwd/bwd chain split (math VERIFIED, absmax 0.0 every round) but
//   always slower: R20 VGPR 120; R21 96 + dead wave; R22 VGPR 76 yet 80us.
//   Fit across R19/R21/R22: perf tracks GATHER WAVE COUNT, not chain length
//   -> the register-direct gather is the gc co-pole (~12us/half-chunk
//   contended): lane=t-row, rows 32KB apart -> every frag load = 64
//   scattered cache lines. Chain fusion (R18) only helped when chain > gather.
// R23 (this round): COALESCE the gather; keep the verified split; VGPR<=76.
//   (a) LDS-staged gather, per-wave vmcnt(0) sync only (no block barriers in
//   the loop): unit = 16 rows x 256B staged via 4 global_load_lds (4 rows x
//   256B contiguous segments each: 16 lines/instr vs 64), then 4 kb of
//   ds_read_b128+MFMA. Full 4-bit XOR slot swizzle (slot = ch ^ row, applied
//   on the GLOBAL SOURCE, same involution on read) -> 2-way banks (free).
//   kb-order unchanged -> bit-identical acc. 4KB LDS slice per wave (16KB
//   total, same as gemm). (b) 4-wave roles: pre-b0 all stage {0,3} (half
//   each); post-b0 w0=fwd ch0 | w1=bwd ch3 | w2/w3 stage {1,2}; post-b1
//   fwd ch1 | bwd ch2 (publish); b2; dot. gemm path byte-identical to R19.

typedef _Float16 f16;
typedef _Float16 f16x8 __attribute__((ext_vector_type(8)));
typedef float f32x4 __attribute__((ext_vector_type(4)));
typedef __attribute__((address_space(1))) void* as1_void_ptr;
typedef __attribute__((address_space(3))) void* as3_void_ptr;

#define TT 512
#define NN 32
#define CC 1296
#define DD 512
#define SS 30
#define CP 1408   // C padded to 11*128 for GEMM tiling (pad rows are zero)
#define LL 61     // 2*S+1 CTC states
#define NORM_SCALE 32.0f
#define LOG2E 1.4426950408889634f
#define LN2   0.6931471805599453f

#define PREP_WBLK (CP / 16)            // 88 c-tiles of 16 (covers pad -> zeros)
#define PREP_ZBLK 16                   // 16 blocks zero sumexp
#define PREP_FBLK (TT * NN / 4)        // 4096 fnorm blocks (4 rows each)

#define GEMM_BLK ((TT * NN / 128) * (CP / 128))   // 128*11 = 1408
#define MEGA_GC  NN                                // 32 gather+ctc blocks
#define MEGA_BLK (MEGA_GC + GEMM_BLK)              // 1440

__device__ __forceinline__ float fexp2(float x) { return __builtin_amdgcn_exp2f(x); }
__device__ __forceinline__ float flog2(float x) { return __builtin_amdgcn_logf(x); }

// whole-wave shift-right-by-1 (lane s <- lane s-1; lane 0 gets 0): ctrl 0x138.
__device__ __forceinline__ double dpp_sr1_zero64(double x) {
    long long b = __double_as_longlong(x);
    int lo = (int)(b & 0xFFFFFFFFLL);
    int hi = (int)(b >> 32);
    int lo2 = __builtin_amdgcn_update_dpp(0, lo, 0x138, 0xF, 0xF, false);
    int hi2 = __builtin_amdgcn_update_dpp(0, hi, 0x138, 0xF, 0xF, false);
    return __longlong_as_double(((long long)hi2 << 32) |
                                (unsigned long long)(unsigned int)lo2);
}
// whole-wave shift-left-by-1 (lane s <- lane s+1; lane 63 gets 0): ctrl 0x130.
__device__ __forceinline__ double dpp_sl1_zero64(double x) {
    long long b = __double_as_longlong(x);
    int lo = (int)(b & 0xFFFFFFFFLL);
    int hi = (int)(b >> 32);
    int lo2 = __builtin_amdgcn_update_dpp(0, lo, 0x130, 0xF, 0xF, false);
    int hi2 = __builtin_amdgcn_update_dpp(0, hi, 0x130, 0xF, 0xF, false);
    return __longlong_as_double(((long long)hi2 << 32) |
                                (unsigned long long)(unsigned int)lo2);
}
// one level of DPP row-shr int max (identity 0; operands are >=0 hi-words)
template <int CTRL>
__device__ __forceinline__ int dpp_imax_level(int m) {
    int t = __builtin_amdgcn_update_dpp(0, m, CTRL, 0xF, 0xF, false);
    return m > t ? m : t;
}
// exact pow2 renorm of a nonneg f64 wave vector; accumulates exponent in Mi.
__device__ __forceinline__ void renorm_d(double& x, int& Mi) {
    int h = (int)(__double_as_longlong(x) >> 32);   // x>=0: hi-word monotone
    h = dpp_imax_level<0x111>(h);
    h = dpp_imax_level<0x112>(h);
    h = dpp_imax_level<0x114>(h);
    h = dpp_imax_level<0x118>(h);        // row max in lanes 15/31/47/63
    int r0 = __builtin_amdgcn_readlane(h, 15);
    int r1 = __builtin_amdgcn_readlane(h, 31);
    int r2 = __builtin_amdgcn_readlane(h, 47);
    int r3 = __builtin_amdgcn_readlane(h, 63);
    int mx = max(max(r0, r1), max(r2, r3));
    int e11 = mx >> 20;                  // biased 11-bit exponent
    double scale = __longlong_as_double((long long)(2046 - e11) << 52);
    x *= scale;
    Mi += e11 - 1023;
}

// ---- fused prep: W column-norm + transpose to f16 (atomic-free, per-block
//      column ownership), feats row-normalize -> f16, sumexp zeroing. ----
__global__ __launch_bounds__(256) void prep_kernel(const float* __restrict__ W,
                                                   const float* __restrict__ feats,
                                                   f16* __restrict__ wt,
                                                   f16* __restrict__ fn,
                                                   float* __restrict__ sumexp) {
    int bx = blockIdx.x, tid = threadIdx.x;
    if (bx < PREP_WBLK) {
        __shared__ float red[256];
        __shared__ float rqs[16];
        int c0 = bx * 16;
        int cl = tid & 15, dg = tid >> 4;
        int c = c0 + cl;
        float ss = 0.f;
        if (c < CC) {
            for (int d = dg; d < DD; d += 16) {
                float v = W[(size_t)d * CC + c];
                ss += v * v;
            }
        }
        red[tid] = ss;
        __syncthreads();
        if (tid < 16) {
            float s2 = 0.f;
            #pragma unroll
            for (int k = 0; k < 16; ++k) s2 += red[tid + 16 * k];
            rqs[tid] = rsqrtf(s2);
        }
        __syncthreads();
        int c_loc = tid >> 4, dl = tid & 15;
        int cc = c0 + c_loc;
        float rq = rqs[c_loc];
        #pragma unroll 4
        for (int it = 0; it < 32; ++it) {
            int d = dl + it * 16;
            float v = (cc < CC) ? W[(size_t)d * CC + cc] * rq : 0.f;
            wt[(size_t)cc * DD + d] = (f16)v;
        }
    } else if (bx < PREP_WBLK + PREP_ZBLK) {
        int zb = bx - PREP_WBLK;
        float4 z = {0.f, 0.f, 0.f, 0.f};
        ((float4*)sumexp)[zb * 256 + tid] = z;   // 16*256*16B = 64KB
    } else {
        int fb = bx - PREP_WBLK - PREP_ZBLK;
        int wv = (fb * 256 + tid) >> 6;  // row id, 0..16383
        int lane = tid & 63;
        const float4* src = (const float4*)(feats + (size_t)wv * DD) + lane * 2;
        float4 a = src[0], b = src[1];
        float ss = a.x*a.x + a.y*a.y + a.z*a.z + a.w*a.w
                 + b.x*b.x + b.y*b.y + b.z*b.z + b.w*b.w;
        #pragma unroll
        for (int off = 32; off; off >>= 1) ss += __shfl_xor(ss, off);
        float r = rsqrtf(ss);
        f16x8 o;
        o[0]=(f16)(a.x*r); o[1]=(f16)(a.y*r); o[2]=(f16)(a.z*r); o[3]=(f16)(a.w*r);
        o[4]=(f16)(b.x*r); o[5]=(f16)(b.y*r); o[6]=(f16)(b.z*r); o[7]=(f16)(b.w*r);
        *(f16x8*)(fn + (size_t)wv * DD + lane * 8) = o;
    }
}

// ---- LDS-staged coalesced gather of 64 t-rows (one half-chunk), per-wave
//      vmcnt sync only. Slice sl = 2048 f16 (4KB), wave-private.
//      LDS layout: (row, slot) at f16 off row*128 + slot*8, where slot holds
//      d-channel ch = slot ^ row (full 4-bit XOR -> 2-way banks on read).
//      Staged via 4 global_load_lds per unit (4 rows x 256B each, source
//      pre-swizzled). MFMA kb order 0..15 ascending -> bit-identical acc. ----
__device__ __forceinline__ void gather_half_lds(f16* sl,
                                                const f16* __restrict__ pb0,
                                                const f16* __restrict__ pb1,
                                                const f16* __restrict__ A,
                                                float* __restrict__ lp_lab,
                                                int n, int c, int rbase, int lane) {
    int lm = lane & 15, hi = lane >> 4;
    int srow = lane >> 4;                    // 0..3: row within 4-row group
    #pragma unroll 1
    for (int i = 0; i < 4; ++i) {            // 4 tiles of 16 rows
        f32x4 a0 = {0.f, 0.f, 0.f, 0.f};
        f32x4 a1 = {0.f, 0.f, 0.f, 0.f};
        int trow0 = c * 128 + rbase + i * 16;
        #pragma unroll 1
        for (int q = 0; q < 4; ++q) {        // d-quarters (kb 4q..4q+3)
            // prior unit's ds_reads must finish before slice overwrite
            asm volatile("s_waitcnt lgkmcnt(0)" ::: "memory");
            __builtin_amdgcn_sched_barrier(0);
            #pragma unroll
            for (int k = 0; k < 4; ++k) {    // 4 rows x 256B per instr
                int rloc = k * 4 + srow;     // row within tile, 0..15
                int ch = (lane & 15) ^ rloc; // source channel pre-swizzle
                const f16* src = A + ((size_t)((trow0 + rloc) * NN + n)) * DD
                               + q * 128 + ch * 8;
                __builtin_amdgcn_global_load_lds((as1_void_ptr)src,
                    (as3_void_ptr)(sl + k * 512), 16, 0, 0);
            }
            asm volatile("s_waitcnt vmcnt(0)" ::: "memory");
            __builtin_amdgcn_sched_barrier(0);
            #pragma unroll
            for (int kq = 0; kq < 4; ++kq) {
                int kb = q * 4 + kq;
                f16x8 bf0 = *(const f16x8*)(pb0 + kb * 32);
                f16x8 bf1 = *(const f16x8*)(pb1 + kb * 32);
                int slot = (kq * 4 + hi) ^ lm;          // read-side involution
                f16x8 af = *(const f16x8*)(sl + lm * 128 + slot * 8);
                a0 = __builtin_amdgcn_mfma_f32_16x16x32_f16(af, bf0, a0, 0, 0, 0);
                a1 = __builtin_amdgcn_mfma_f32_16x16x32_f16(af, bf1, a1, 0, 0, 0);
            }
        }
        // write-out tile i: col jc = jn*16+lm, rows t = trow0 + hi*4 + r
        #pragma unroll
        for (int jn = 0; jn < 2; ++jn) {
            int jc = jn * 16 + lm;
            if (jc >= 31) continue;
            f32x4 av = jn ? a1 : a0;
            float4 o;
            o.x = av[0] * (NORM_SCALE * LOG2E);
            o.y = av[1] * (NORM_SCALE * LOG2E);
            o.z = av[2] * (NORM_SCALE * LOG2E);
            o.w = av[3] * (NORM_SCALE * LOG2E);
            *(float4*)&lp_lab[((size_t)n * 31 + jc) * TT + trow0 + hi * 4] = o;
        }
    }
}

// ---- mega (256-thread blocks): blocks 0..31 = {4-wave gc: pre-b0 all stage
//      chunks {0,3} (half each); post-b0 w0 fwd ch0 | w1 bwd ch3 | w2/w3
//      stage {1,2}; post-b1 fwd ch1 | bwd ch2 (publish); b2; dot};
//      blocks 32..1439 = gemm+sumexp, byte-identical to R19. ----
__global__ __launch_bounds__(256) void mega_kernel(const f16* __restrict__ A,
                                                   const f16* __restrict__ B,
                                                   const int* __restrict__ labels,
                                                   const int* __restrict__ in_lens,
                                                   const int* __restrict__ lab_lens,
                                                   float* __restrict__ sumexp,
                                                   float* __restrict__ lp_lab,
                                                   double* __restrict__ part) {
    __shared__ __align__(16) f16 sm[8192];   // 16KB: gemm tiles | gc 4x4KB slices
    int bx = blockIdx.x;
    int tid = threadIdx.x;
    int w = tid >> 6, lane = tid & 63;
    int lm = lane & 15, hi = lane >> 4;
    int sw = (lm >> 1) & 3;                // fragment-read channel swizzle

    if (bx >= MEGA_GC) {
        // ================= GEMM section (identical since R19) ===============
        int j = bx - MEGA_GC;
        int x = j & 7, rr = j >> 3;            // XCD-aware: per-XCD bm range
        int bm = x * 16 + (rr & 15);
        int bn = rr >> 4;                      // [0,11)
        int wm = w >> 1, wn = w & 1;           // 2x2 wave grid -> 64x64 per wave
        f32x4 acc[4][4];
        f32x4 zero = {0.f, 0.f, 0.f, 0.f};
        #pragma unroll
        for (int i = 0; i < 4; ++i)
            #pragma unroll
            for (int jj = 0; jj < 4; ++jj) acc[i][jj] = zero;

        for (int kb = 0; kb < 16; ++kb) {      // K=512, BK=32 (one MFMA K-step)
            #pragma unroll
            for (int p = 0; p < 2; ++p) {
                int s = p * 256 + tid;
                int row = s >> 2;
                int ch = (s & 3) ^ ((row >> 1) & 3);   // swizzled source channel
                const f16* ga = A + (size_t)(bm * 128 + row) * DD + kb * 32 + ch * 8;
                const f16* gb = B + (size_t)(bn * 128 + row) * DD + kb * 32 + ch * 8;
                __builtin_amdgcn_global_load_lds((as1_void_ptr)ga,
                    (as3_void_ptr)&sm[(p * 256 + w * 64) * 8], 16, 0, 0);
                __builtin_amdgcn_global_load_lds((as1_void_ptr)gb,
                    (as3_void_ptr)&sm[4096 + (p * 256 + w * 64) * 8], 16, 0, 0);
            }
            __syncthreads();
            f16x8 af[4], bf[4];
            #pragma unroll
            for (int i = 0; i < 4; ++i)
                af[i] = *(const f16x8*)&sm[(wm * 64 + i * 16 + lm) * 32 + (hi ^ sw) * 8];
            #pragma unroll
            for (int jj = 0; jj < 4; ++jj)
                bf[jj] = *(const f16x8*)&sm[4096 + (wn * 64 + jj * 16 + lm) * 32 + (hi ^ sw) * 8];
            #pragma unroll
            for (int i = 0; i < 4; ++i)
                #pragma unroll
                for (int jj = 0; jj < 4; ++jj)
                    acc[i][jj] = __builtin_amdgcn_mfma_f32_16x16x32_f16(af[i], bf[jj], acc[i][jj], 0, 0, 0);
            __syncthreads();
        }
        #pragma unroll
        for (int i = 0; i < 4; ++i) {
            float rs[4] = {0.f, 0.f, 0.f, 0.f};
            #pragma unroll
            for (int jj = 0; jj < 4; ++jj) {
                int c = bn * 128 + wn * 64 + jj * 16 + lm;   // C/D: col = lane&15
                bool ok = (c < CC);
                #pragma unroll
                for (int r = 0; r < 4; ++r)
                    rs[r] += ok ? fexp2(acc[i][jj][r] * (NORM_SCALE * LOG2E)) : 0.f;
            }
            #pragma unroll
            for (int off = 1; off < 16; off <<= 1) {
                #pragma unroll
                for (int r = 0; r < 4; ++r) rs[r] += __shfl_xor(rs[r], off);
            }
            if (lm == 0) {
                int rowb = bm * 128 + wm * 64 + i * 16 + hi * 4;
                #pragma unroll
                for (int r = 0; r < 4; ++r) atomicAdd(&sumexp[rowb + r], rs[r]);
            }
        }
        return;
    }

    // ================= gather + fwd/bwd ctc section (block n = bx) ==========
    int n = bx;
    // per-lane B row pointers (label classes; L2-hot wt rows)
    int cls0 = (lm == 0) ? 0 : labels[n * SS + lm - 1];       // j = lm
    int cls1 = (lm >= 15) ? 0 : labels[n * SS + lm + 15];     // j = 16+lm
    const f16* pb0 = B + (size_t)cls0 * DD + hi * 8;
    const f16* pb1 = B + (size_t)cls1 * DD + hi * 8;
    f16* sl = sm + w * 2048;                 // 4KB wave-private slice

    // pre-b0: stage chunks {0,3}, one half per wave
    __builtin_amdgcn_s_setprio(2);
    gather_half_lds(sl, pb0, pb1, A, lp_lab, n,
                    (w < 2) ? 0 : 3, (w & 1) * 64, lane);
    __builtin_amdgcn_s_setprio(0);
    __syncthreads();                         // b0: chunks 0,3 published

    if (w >= 2) {
        // post-b0: stage chunks 1 then 2 (halves by w&1)
        __builtin_amdgcn_s_setprio(2);
        gather_half_lds(sl, pb0, pb1, A, lp_lab, n, 1, (w & 1) * 64, lane);
        gather_half_lds(sl, pb0, pb1, A, lp_lab, n, 2, (w & 1) * 64, lane);
        __builtin_amdgcn_s_setprio(0);
        __syncthreads();                     // b1: chunks 1,2 published
        __syncthreads();                     // b2 (match chain waves)
        return;
    }

    int s = lane;            // 64 lanes; states 0..60 valid
    bool valid = s < LL;
    int ext = (valid && (s & 1)) ? labels[n * SS + (s >> 1)] : 0;
    int jmap = (valid && (s & 1)) ? ((s >> 1) + 1) : 0;   // state -> class slot
    int Tin = in_lens[n];    // wave-uniform; in [481,512]
    const float* lpr = lp_lab + ((size_t)n * 31 + jmap) * TT;
    double* vb = (double*)sm;                // dot buffer (w0 slice; safe: only
                                             // used after all slice reads done)

    if (w == 0) {
        // ---------------- forward: alpha over t = 0..255 --------------------
        int ext2 = __shfl_up(ext, 2);
        double skipd = ((s >= 2) && valid && (ext != ext2)) ? 1.0 : 0.0;
        double sk1 = dpp_sr1_zero64(skipd);
        double sk2 = dpp_sr1_zero64(sk1);
        double kk2 = skipd * sk2;
        const float4* g4 = (const float4*)lpr;
        double beta = 0.0;
        int Mif = 0;

        auto stepL = [&](float lp) {
            double P = (double)fexp2(lp);
            double b1 = dpp_sr1_zero64(beta);
            double b2 = dpp_sr1_zero64(b1);
            beta = (beta + b1 + b2 * skipd) * P;
        };
        auto step2 = [&](float lp1, float lp2) {
            double q  = (double)fexp2(lp1);
            double P2 = (double)fexp2(lp2);
            double q1 = dpp_sr1_zero64(q);
            double q2 = dpp_sr1_zero64(q1);
            double c1 = q + q1;
            double c2 = fma(skipd, q + q2, q1);
            double c3 = fma(sk1, q1, skipd * q2);
            double c4 = kk2 * q2;
            double b1 = dpp_sr1_zero64(beta);
            double b2 = dpp_sr1_zero64(b1);
            double b3 = dpp_sr1_zero64(b2);
            double b4 = dpp_sr1_zero64(b3);
            double u = fma(c1, b1, q * beta);
            double v2 = fma(c3, b3, c2 * b2);
            beta = (u + fma(c4, b4, v2)) * P2;
        };

        __builtin_amdgcn_s_setprio(3);
        float4 q0 = g4[0];
        beta = (s <= 1) ? (double)fexp2(q0.x) : 0.0;
        stepL(q0.y); stepL(q0.z); stepL(q0.w);   // t = 1..3
        renorm_d(beta, Mif);
        float4 cu = g4[1];
        for (int gi = 1; gi <= 31; ++gi) {       // t = 4..127 (chunk 0)
            float4 nx = g4[gi < 31 ? gi + 1 : 31];
            step2(cu.x, cu.y); step2(cu.z, cu.w);
            if (gi & 1) renorm_d(beta, Mif);
            cu = nx;
        }
        __syncthreads();                     // b1: chunks 1,2 ready
        cu = g4[32];
        for (int gi = 32; gi <= 63; ++gi) {      // t = 128..255 (chunk 1)
            float4 nx = g4[gi < 63 ? gi + 1 : 63];
            step2(cu.x, cu.y); step2(cu.z, cu.w);
            if (gi & 1) renorm_d(beta, Mif);
            cu = nx;
        }
        renorm_d(beta, Mif);
        __syncthreads();                     // b2: bwd vector published
        __builtin_amdgcn_s_setprio(0);
        double pr = beta * vb[s];            // v[s>=LL] == 0: garbage excluded
        #pragma unroll
        for (int off = 32; off; off >>= 1) pr += __shfl_xor(pr, off);
        if (s == 0) {
            long long bb = __double_as_longlong(pr);
            int e = (int)(bb >> 52) - 1023;
            double mant = __longlong_as_double((bb & 0xFFFFFFFFFFFFFLL) | (1023LL << 52));
            part[n] = (double)flog2((float)mant) + (double)(e + Mif) + vb[64];
        }
        return;
    }

    // ---------------- backward: v^T <- v^T A_t, t = Tin-1 .. 256 ------------
    // Lean 1-step form (verified R20/R22): u = p*v; v = u + u[s+1] + k2*u[s+2].
    {
        float maskf = valid ? 1.f : 0.f;     // p=0 outside states: no garbage
        int extd2 = __shfl_down(ext, 2);
        double k2d = ((s + 2) < LL && extd2 != ext) ? 1.0 : 0.0;  // k[s+2]
        int Ln = 2 * lab_lens[n] + 1;
        double v = (s == Ln - 1 || s == Ln - 2) ? 1.0 : 0.0;
        int Mib = 0;

        auto step1b = [&](float lph) {
            float p = maskf * fexp2(lph);
            double u  = (double)p * v;
            double u1 = dpp_sl1_zero64(u);
            double u2 = dpp_sl1_zero64(u1);
            v = fma(k2d, u2, u + u1);
        };

        __builtin_amdgcn_s_setprio(3);
        int tc = Tin - 1;
        int rnc = 0;
        while (tc >= 384) {                  // phase A: chunk 3
            step1b(lpr[tc]);
            if (((++rnc) & 7) == 0) renorm_d(v, Mib);
            --tc;
        }
        renorm_d(v, Mib);
        __syncthreads();                     // b1: chunk 2 ready
        while (tc >= 256) {                  // phase B: chunk 2 (128 steps)
            step1b(lpr[tc]);
            if (((++rnc) & 7) == 0) renorm_d(v, Mib);
            --tc;
        }
        renorm_d(v, Mib);
        vb[s] = v;
        if (s == 0) vb[64] = (double)Mib;
        __builtin_amdgcn_s_setprio(0);
        __syncthreads();                     // b2: publish v + Mi_b
        return;
    }
}

// ---- final: Msum per n (f64, fixed order) + nll + deterministic sum ----
__global__ __launch_bounds__(1024) void final_kernel(const float* __restrict__ sumexp,
                                                     const int* __restrict__ in_lens,
                                                     const double* __restrict__ part,
                                                     float* __restrict__ out) {
    int tid = threadIdx.x;
    int v = tid >> 6, lane = tid & 63;     // 16 waves, 2 samples each
    __shared__ float nl[NN];
    #pragma unroll
    for (int k = 0; k < 2; ++k) {
        int n = v * 2 + k;
        int Tin = in_lens[n];
        double ms = 0.0;
        for (int t = lane; t < Tin; t += 64)
            ms += (double)flog2(sumexp[(size_t)t * NN + n]);
        #pragma unroll
        for (int off = 32; off; off >>= 1) ms += __shfl_xor(ms, off);
        if (lane == 0) nl[n] = (float)(-(part[n] - ms) * LN2);
    }
    __syncthreads();
    if (tid == 0) {
        float t = 0.f;
        for (int i = 0; i < NN; ++i) t += nl[i];
        out[0] = t;
    }
}

extern "C" void kernel_launch(void* const* d_in, const int* in_sizes, int n_in,
                              void* d_out, int out_size, void* d_ws, size_t ws_size,
                              hipStream_t stream) {
    const float* feats        = (const float*)d_in[0];
    const float* W            = (const float*)d_in[1];
    const int*   labeling     = (const int*)d_in[2];
    const int*   logit_lgts   = (const int*)d_in[3];
    const int*   labeling_lgts= (const int*)d_in[4];
    float* out = (float*)d_out;
    char* ws = (char*)d_ws;

    size_t off = 0;
    f16*   wt     = (f16*)(ws + off);   off += (size_t)CP * DD * 2;        // 1.44 MB
    f16*   fn     = (f16*)(ws + off);   off += (size_t)TT * NN * DD * 2;   // 16.8 MB
    float* sumexp = (float*)(ws + off); off += (size_t)TT * NN * 4;        // 64 KB
    float* lp_lab = (float*)(ws + off); off += (size_t)NN * 31 * TT * 4;   // 2.0 MB
    double* part  = (double*)(ws + off); off += NN * 8;

    prep_kernel<<<PREP_WBLK + PREP_ZBLK + PREP_FBLK, 256, 0, stream>>>(
        W, feats, wt, fn, sumexp);
    mega_kernel<<<MEGA_BLK, 256, 0, stream>>>(fn, wt, labeling, logit_lgts,
                                              labeling_lgts, sumexp, lp_lab, part);
    final_kernel<<<1, 1024, 0, stream>>>(sumexp, logit_lgts, part, out);

    (void)in_sizes; (void)n_in; (void)out_size; (void)ws_size;
}

// Round 13
// 180.785 us; speedup vs baseline: 1.0141x; 1.0141x over previous
//
#include <hip/hip_runtime.h>
#include <stdint.h>
#include <stddef.h>

// RadialCTC: cosine logits (norm_scale=32) -> log_softmax -> CTC(sum).
// Strategy: never materialize the (16384 x 1296) logits. GEMM (f16 MFMA)
// computes per-row sum(exp(logit)) fused in the epilogue; label log-probs via
// small f16 MFMA gather-GEMM; CTC alpha recursion one wave per sample.
// R9: linear f64 + pow2 renorm ctc. R11: XOR channel-slot LDS swizzle (gemm).
// R14: log2(sumexp) factored out (Msum). R15 FAILED: acquire-spin L2 storms.
// R18 (154.2): fused 2-step fwd chain: mega 54.9. R19 (153.2): XCD remap;
//   mega 54.4, VGPR 76. BEST so far.
// R20-R23: fwd/bwd split fused into mega: VERIFIED math (absmax 0.0 x4) but
//   all regressions (70/64/80/84us). Consolidated model: a gc block
//   co-resident with ~5 gemm waves/SIMD runs 4-6x slower than solo -- chain
//   ~220cyc/step, gather 2-4x. The FUSION is the problem, not the parts.
// R24 (this round): de-fuse the chain. R12 proved dispatch count is free.
//   gg dispatch = 1408 gemm blocks (R19 verbatim) + 32 PURE gather blocks
//   (4 waves x NT=2 register-direct, verified code, zero barriers, no
//   chains; VGPR stays 76). Standalone ctc dispatch: 32 blocks x 128thr,
//   w0 fwd t=0..255 (R18 step2, barriers removed) + w1 bwd t=Tin-1..256
//   (R22 step1b), one barrier, cross-wave dot -- UNCONTENDED, so the
//   verified split finally pays (~6-10us solo). prep/final unchanged.

typedef _Float16 f16;
typedef _Float16 f16x8 __attribute__((ext_vector_type(8)));
typedef float f32x4 __attribute__((ext_vector_type(4)));
typedef __attribute__((address_space(1))) void* as1_void_ptr;
typedef __attribute__((address_space(3))) void* as3_void_ptr;

#define TT 512
#define NN 32
#define CC 1296
#define DD 512
#define SS 30
#define CP 1408   // C padded to 11*128 for GEMM tiling (pad rows are zero)
#define LL 61     // 2*S+1 CTC states
#define NORM_SCALE 32.0f
#define LOG2E 1.4426950408889634f
#define LN2   0.6931471805599453f

#define PREP_WBLK (CP / 16)            // 88 c-tiles of 16 (covers pad -> zeros)
#define PREP_ZBLK 16                   // 16 blocks zero sumexp
#define PREP_FBLK (TT * NN / 4)        // 4096 fnorm blocks (4 rows each)

#define GEMM_BLK ((TT * NN / 128) * (CP / 128))   // 128*11 = 1408
#define GG_GATH  NN                                // 32 pure gather blocks
#define GG_BLK   (GG_GATH + GEMM_BLK)              // 1440

__device__ __forceinline__ float fexp2(float x) { return __builtin_amdgcn_exp2f(x); }
__device__ __forceinline__ float flog2(float x) { return __builtin_amdgcn_logf(x); }

// whole-wave shift-right-by-1 (lane s <- lane s-1; lane 0 gets 0): ctrl 0x138.
__device__ __forceinline__ double dpp_sr1_zero64(double x) {
    long long b = __double_as_longlong(x);
    int lo = (int)(b & 0xFFFFFFFFLL);
    int hi = (int)(b >> 32);
    int lo2 = __builtin_amdgcn_update_dpp(0, lo, 0x138, 0xF, 0xF, false);
    int hi2 = __builtin_amdgcn_update_dpp(0, hi, 0x138, 0xF, 0xF, false);
    return __longlong_as_double(((long long)hi2 << 32) |
                                (unsigned long long)(unsigned int)lo2);
}
// whole-wave shift-left-by-1 (lane s <- lane s+1; lane 63 gets 0): ctrl 0x130.
__device__ __forceinline__ double dpp_sl1_zero64(double x) {
    long long b = __double_as_longlong(x);
    int lo = (int)(b & 0xFFFFFFFFLL);
    int hi = (int)(b >> 32);
    int lo2 = __builtin_amdgcn_update_dpp(0, lo, 0x130, 0xF, 0xF, false);
    int hi2 = __builtin_amdgcn_update_dpp(0, hi, 0x130, 0xF, 0xF, false);
    return __longlong_as_double(((long long)hi2 << 32) |
                                (unsigned long long)(unsigned int)lo2);
}
// one level of DPP row-shr int max (identity 0; operands are >=0 hi-words)
template <int CTRL>
__device__ __forceinline__ int dpp_imax_level(int m) {
    int t = __builtin_amdgcn_update_dpp(0, m, CTRL, 0xF, 0xF, false);
    return m > t ? m : t;
}
// exact pow2 renorm of a nonneg f64 wave vector; accumulates exponent in Mi.
__device__ __forceinline__ void renorm_d(double& x, int& Mi) {
    int h = (int)(__double_as_longlong(x) >> 32);   // x>=0: hi-word monotone
    h = dpp_imax_level<0x111>(h);
    h = dpp_imax_level<0x112>(h);
    h = dpp_imax_level<0x114>(h);
    h = dpp_imax_level<0x118>(h);        // row max in lanes 15/31/47/63
    int r0 = __builtin_amdgcn_readlane(h, 15);
    int r1 = __builtin_amdgcn_readlane(h, 31);
    int r2 = __builtin_amdgcn_readlane(h, 47);
    int r3 = __builtin_amdgcn_readlane(h, 63);
    int mx = max(max(r0, r1), max(r2, r3));
    int e11 = mx >> 20;                  // biased 11-bit exponent
    double scale = __longlong_as_double((long long)(2046 - e11) << 52);
    x *= scale;
    Mi += e11 - 1023;
}

// ---- fused prep: W column-norm + transpose to f16 (atomic-free, per-block
//      column ownership), feats row-normalize -> f16, sumexp zeroing. ----
__global__ __launch_bounds__(256) void prep_kernel(const float* __restrict__ W,
                                                   const float* __restrict__ feats,
                                                   f16* __restrict__ wt,
                                                   f16* __restrict__ fn,
                                                   float* __restrict__ sumexp) {
    int bx = blockIdx.x, tid = threadIdx.x;
    if (bx < PREP_WBLK) {
        __shared__ float red[256];
        __shared__ float rqs[16];
        int c0 = bx * 16;
        int cl = tid & 15, dg = tid >> 4;
        int c = c0 + cl;
        float ss = 0.f;
        if (c < CC) {
            for (int d = dg; d < DD; d += 16) {
                float v = W[(size_t)d * CC + c];
                ss += v * v;
            }
        }
        red[tid] = ss;
        __syncthreads();
        if (tid < 16) {
            float s2 = 0.f;
            #pragma unroll
            for (int k = 0; k < 16; ++k) s2 += red[tid + 16 * k];
            rqs[tid] = rsqrtf(s2);
        }
        __syncthreads();
        int c_loc = tid >> 4, dl = tid & 15;
        int cc = c0 + c_loc;
        float rq = rqs[c_loc];
        #pragma unroll 4
        for (int it = 0; it < 32; ++it) {
            int d = dl + it * 16;
            float v = (cc < CC) ? W[(size_t)d * CC + cc] * rq : 0.f;
            wt[(size_t)cc * DD + d] = (f16)v;
        }
    } else if (bx < PREP_WBLK + PREP_ZBLK) {
        int zb = bx - PREP_WBLK;
        float4 z = {0.f, 0.f, 0.f, 0.f};
        ((float4*)sumexp)[zb * 256 + tid] = z;   // 16*256*16B = 64KB
    } else {
        int fb = bx - PREP_WBLK - PREP_ZBLK;
        int wv = (fb * 256 + tid) >> 6;  // row id, 0..16383
        int lane = tid & 63;
        const float4* src = (const float4*)(feats + (size_t)wv * DD) + lane * 2;
        float4 a = src[0], b = src[1];
        float ss = a.x*a.x + a.y*a.y + a.z*a.z + a.w*a.w
                 + b.x*b.x + b.y*b.y + b.z*b.z + b.w*b.w;
        #pragma unroll
        for (int off = 32; off; off >>= 1) ss += __shfl_xor(ss, off);
        float r = rsqrtf(ss);
        f16x8 o;
        o[0]=(f16)(a.x*r); o[1]=(f16)(a.y*r); o[2]=(f16)(a.z*r); o[3]=(f16)(a.w*r);
        o[4]=(f16)(b.x*r); o[5]=(f16)(b.y*r); o[6]=(f16)(b.z*r); o[7]=(f16)(b.w*r);
        *(f16x8*)(fn + (size_t)wv * DD + lane * 8) = o;
    }
}

// ---- one gather pass: NT 16-row t-tiles of chunk c starting at rbase.
//      Register-direct MFMA frags (A row=lane&15, k=(lane>>4)*8).
//      Verified R19/R22. ----
template <int NT>
__device__ __forceinline__ void gather_chunk(const f16* __restrict__ pb0,
                                             const f16* __restrict__ pb1,
                                             const f16* __restrict__ A,
                                             float* __restrict__ lp_lab,
                                             int n, int c, int rbase, int lane) {
    int lm = lane & 15, hi = lane >> 4;
    const f16* pa0 = A + ((size_t)(c * 128 + rbase + lm) * NN + n) * DD + hi * 8;
    f32x4 acc[NT][2];
    #pragma unroll
    for (int i = 0; i < NT; ++i) {
        acc[i][0] = (f32x4){0.f, 0.f, 0.f, 0.f};
        acc[i][1] = (f32x4){0.f, 0.f, 0.f, 0.f};
    }
    for (int kb = 0; kb < 16; ++kb) {
        f16x8 bf0 = *(const f16x8*)(pb0 + kb * 32);
        f16x8 bf1 = *(const f16x8*)(pb1 + kb * 32);
        #pragma unroll
        for (int i = 0; i < NT; ++i) {
            f16x8 af = *(const f16x8*)(pa0 + (size_t)(i * 16) * NN * DD + kb * 32);
            acc[i][0] = __builtin_amdgcn_mfma_f32_16x16x32_f16(af, bf0, acc[i][0], 0, 0, 0);
            acc[i][1] = __builtin_amdgcn_mfma_f32_16x16x32_f16(af, bf1, acc[i][1], 0, 0, 0);
        }
    }
    #pragma unroll
    for (int i = 0; i < NT; ++i) {
        #pragma unroll
        for (int jn = 0; jn < 2; ++jn) {
            int jc = jn * 16 + lm;
            if (jc >= 31) continue;
            float4 o;
            o.x = acc[i][jn][0] * (NORM_SCALE * LOG2E);
            o.y = acc[i][jn][1] * (NORM_SCALE * LOG2E);
            o.z = acc[i][jn][2] * (NORM_SCALE * LOG2E);
            o.w = acc[i][jn][3] * (NORM_SCALE * LOG2E);
            *(float4*)&lp_lab[((size_t)n * 31 + jc) * TT
                              + c * 128 + rbase + i * 16 + hi * 4] = o;
        }
    }
}

// ---- gg: blocks 0..31 = pure gather (4 waves x NT=2, no barriers, no
//      chains); blocks 32..1439 = gemm+sumexp (16KB LDS, XOR swizzle,
//      XCD-aware bm grouping) - byte-identical to R19. ----
__global__ __launch_bounds__(256) void gg_kernel(const f16* __restrict__ A,
                                                 const f16* __restrict__ B,
                                                 const int* __restrict__ labels,
                                                 float* __restrict__ sumexp,
                                                 float* __restrict__ lp_lab) {
    __shared__ __align__(16) f16 sm[8192];   // 16 KB (gemm only)
    int bx = blockIdx.x;
    int tid = threadIdx.x;
    int w = tid >> 6, lane = tid & 63;
    int lm = lane & 15, hi = lane >> 4;
    int sw = (lm >> 1) & 3;                // fragment-read channel swizzle

    if (bx >= GG_GATH) {
        // ================= GEMM section (identical since R19) ===============
        int j = bx - GG_GATH;
        int x = j & 7, rr = j >> 3;            // XCD-aware: per-XCD bm range
        int bm = x * 16 + (rr & 15);
        int bn = rr >> 4;                      // [0,11)
        int wm = w >> 1, wn = w & 1;           // 2x2 wave grid -> 64x64 per wave
        f32x4 acc[4][4];
        f32x4 zero = {0.f, 0.f, 0.f, 0.f};
        #pragma unroll
        for (int i = 0; i < 4; ++i)
            #pragma unroll
            for (int jj = 0; jj < 4; ++jj) acc[i][jj] = zero;

        for (int kb = 0; kb < 16; ++kb) {      // K=512, BK=32 (one MFMA K-step)
            #pragma unroll
            for (int p = 0; p < 2; ++p) {
                int s = p * 256 + tid;
                int row = s >> 2;
                int ch = (s & 3) ^ ((row >> 1) & 3);   // swizzled source channel
                const f16* ga = A + (size_t)(bm * 128 + row) * DD + kb * 32 + ch * 8;
                const f16* gb = B + (size_t)(bn * 128 + row) * DD + kb * 32 + ch * 8;
                __builtin_amdgcn_global_load_lds((as1_void_ptr)ga,
                    (as3_void_ptr)&sm[(p * 256 + w * 64) * 8], 16, 0, 0);
                __builtin_amdgcn_global_load_lds((as1_void_ptr)gb,
                    (as3_void_ptr)&sm[4096 + (p * 256 + w * 64) * 8], 16, 0, 0);
            }
            __syncthreads();
            f16x8 af[4], bf[4];
            #pragma unroll
            for (int i = 0; i < 4; ++i)
                af[i] = *(const f16x8*)&sm[(wm * 64 + i * 16 + lm) * 32 + (hi ^ sw) * 8];
            #pragma unroll
            for (int jj = 0; jj < 4; ++jj)
                bf[jj] = *(const f16x8*)&sm[4096 + (wn * 64 + jj * 16 + lm) * 32 + (hi ^ sw) * 8];
            #pragma unroll
            for (int i = 0; i < 4; ++i)
                #pragma unroll
                for (int jj = 0; jj < 4; ++jj)
                    acc[i][jj] = __builtin_amdgcn_mfma_f32_16x16x32_f16(af[i], bf[jj], acc[i][jj], 0, 0, 0);
            __syncthreads();
        }
        #pragma unroll
        for (int i = 0; i < 4; ++i) {
            float rs[4] = {0.f, 0.f, 0.f, 0.f};
            #pragma unroll
            for (int jj = 0; jj < 4; ++jj) {
                int c = bn * 128 + wn * 64 + jj * 16 + lm;   // C/D: col = lane&15
                bool ok = (c < CC);
                #pragma unroll
                for (int r = 0; r < 4; ++r)
                    rs[r] += ok ? fexp2(acc[i][jj][r] * (NORM_SCALE * LOG2E)) : 0.f;
            }
            #pragma unroll
            for (int off = 1; off < 16; off <<= 1) {
                #pragma unroll
                for (int r = 0; r < 4; ++r) rs[r] += __shfl_xor(rs[r], off);
            }
            if (lm == 0) {
                int rowb = bm * 128 + wm * 64 + i * 16 + hi * 4;
                #pragma unroll
                for (int r = 0; r < 4; ++r) atomicAdd(&sumexp[rowb + r], rs[r]);
            }
        }
        return;
    }

    // ================= pure gather block (n = bx): 4 waves x 32 rows =======
    int n = bx;
    int rbase = w * 32;
    int cls0 = (lm == 0) ? 0 : labels[n * SS + lm - 1];       // j = lm
    int cls1 = (lm >= 15) ? 0 : labels[n * SS + lm + 15];     // j = 16+lm
    const f16* pb0 = B + (size_t)cls0 * DD + hi * 8;
    const f16* pb1 = B + (size_t)cls1 * DD + hi * 8;
    #pragma unroll 1
    for (int c = 0; c < 4; ++c)
        gather_chunk<2>(pb0, pb1, A, lp_lab, n, c, rbase, lane);
}

// ---- ctc: standalone, uncontended. 32 blocks x 128 threads.
//      w0: fwd alpha t=0..255 (R18-verified step2 chain).
//      w1: bwd row recursion t=Tin-1..256 (R22-verified step1b chain).
//      One barrier; cross-wave f64 dot via LDS; part[n] = log2(prob)+Mib. ----
__global__ __launch_bounds__(128) void ctc_kernel(const float* __restrict__ lp_lab,
                                                  const int* __restrict__ labels,
                                                  const int* __restrict__ in_lens,
                                                  const int* __restrict__ lab_lens,
                                                  double* __restrict__ part) {
    __shared__ double vb[65];
    int n = blockIdx.x;
    int tid = threadIdx.x;
    int w = tid >> 6, s = tid & 63;
    bool valid = s < LL;
    int ext = (valid && (s & 1)) ? labels[n * SS + (s >> 1)] : 0;
    int jmap = (valid && (s & 1)) ? ((s >> 1) + 1) : 0;   // state -> class slot
    int Tin = in_lens[n];    // wave-uniform; in [481,512]
    const float* lpr = lp_lab + ((size_t)n * 31 + jmap) * TT;

    if (w == 0) {
        // ---------------- forward: alpha over t = 0..255 --------------------
        int ext2 = __shfl_up(ext, 2);
        double skipd = ((s >= 2) && valid && (ext != ext2)) ? 1.0 : 0.0;
        double sk1 = dpp_sr1_zero64(skipd);
        double sk2 = dpp_sr1_zero64(sk1);
        double kk2 = skipd * sk2;
        const float4* g4 = (const float4*)lpr;
        int Mif = 0;

        auto stepL = [&](double& beta, float lp) {
            double P = (double)fexp2(lp);
            double b1 = dpp_sr1_zero64(beta);
            double b2 = dpp_sr1_zero64(b1);
            beta = (beta + b1 + b2 * skipd) * P;
        };
        auto step2 = [&](double& beta, float lp1, float lp2) {
            double q  = (double)fexp2(lp1);
            double P2 = (double)fexp2(lp2);
            double q1 = dpp_sr1_zero64(q);
            double q2 = dpp_sr1_zero64(q1);
            double c1 = q + q1;
            double c2 = fma(skipd, q + q2, q1);
            double c3 = fma(sk1, q1, skipd * q2);
            double c4 = kk2 * q2;
            double b1 = dpp_sr1_zero64(beta);
            double b2 = dpp_sr1_zero64(b1);
            double b3 = dpp_sr1_zero64(b2);
            double b4 = dpp_sr1_zero64(b3);
            double u = fma(c1, b1, q * beta);
            double v2 = fma(c3, b3, c2 * b2);
            beta = (u + fma(c4, b4, v2)) * P2;
        };

        float4 q0 = g4[0];
        double beta = (s <= 1) ? (double)fexp2(q0.x) : 0.0;
        stepL(beta, q0.y); stepL(beta, q0.z); stepL(beta, q0.w);   // t = 1..3
        renorm_d(beta, Mif);
        float4 cu = g4[1];
        for (int gi = 1; gi <= 63; ++gi) {       // t = 4..255
            float4 nx = g4[gi < 63 ? gi + 1 : 63];
            step2(beta, cu.x, cu.y); step2(beta, cu.z, cu.w);
            if (gi & 1) renorm_d(beta, Mif);
            cu = nx;
        }
        renorm_d(beta, Mif);
        __syncthreads();                     // bwd vector published
        double pr = beta * vb[s];            // v[s>=LL] == 0: garbage excluded
        #pragma unroll
        for (int off = 32; off; off >>= 1) pr += __shfl_xor(pr, off);
        if (s == 0) {
            long long bb = __double_as_longlong(pr);
            int e = (int)(bb >> 52) - 1023;
            double mant = __longlong_as_double((bb & 0xFFFFFFFFFFFFFLL) | (1023LL << 52));
            part[n] = (double)flog2((float)mant) + (double)(e + Mif) + vb[64];
        }
        return;
    }

    // ---------------- backward: v^T <- v^T A_t, t = Tin-1 .. 256 ------------
    // Lean 1-step form (verified R22): u = p*v; v = u + u[s+1] + k2*u[s+2].
    {
        float maskf = valid ? 1.f : 0.f;     // p=0 outside states: no garbage
        int extd2 = __shfl_down(ext, 2);
        double k2d = ((s + 2) < LL && extd2 != ext) ? 1.0 : 0.0;  // k[s+2]
        int Ln = 2 * lab_lens[n] + 1;
        double v = (s == Ln - 1 || s == Ln - 2) ? 1.0 : 0.0;
        int Mib = 0;

        auto step1b = [&](float lph) {
            float p = maskf * fexp2(lph);
            double u  = (double)p * v;
            double u1 = dpp_sl1_zero64(u);
            double u2 = dpp_sl1_zero64(u1);
            v = fma(k2d, u2, u + u1);
        };

        int tc = Tin - 1;
        int rnc = 0;
        while (tc >= 256) {                  // t = Tin-1 .. 256
            step1b(lpr[tc]);
            if (((++rnc) & 7) == 0) renorm_d(v, Mib);
            --tc;
        }
        renorm_d(v, Mib);
        vb[s] = v;
        if (s == 0) vb[64] = (double)Mib;
        __syncthreads();                     // publish v + Mi_b
        return;
    }
}

// ---- final: Msum per n (f64, fixed order) + nll + deterministic sum ----
__global__ __launch_bounds__(1024) void final_kernel(const float* __restrict__ sumexp,
                                                     const int* __restrict__ in_lens,
                                                     const double* __restrict__ part,
                                                     float* __restrict__ out) {
    int tid = threadIdx.x;
    int v = tid >> 6, lane = tid & 63;     // 16 waves, 2 samples each
    __shared__ float nl[NN];
    #pragma unroll
    for (int k = 0; k < 2; ++k) {
        int n = v * 2 + k;
        int Tin = in_lens[n];
        double ms = 0.0;
        for (int t = lane; t < Tin; t += 64)
            ms += (double)flog2(sumexp[(size_t)t * NN + n]);
        #pragma unroll
        for (int off = 32; off; off >>= 1) ms += __shfl_xor(ms, off);
        if (lane == 0) nl[n] = (float)(-(part[n] - ms) * LN2);
    }
    __syncthreads();
    if (tid == 0) {
        float t = 0.f;
        for (int i = 0; i < NN; ++i) t += nl[i];
        out[0] = t;
    }
}

extern "C" void kernel_launch(void* const* d_in, const int* in_sizes, int n_in,
                              void* d_out, int out_size, void* d_ws, size_t ws_size,
                              hipStream_t stream) {
    const float* feats        = (const float*)d_in[0];
    const float* W            = (const float*)d_in[1];
    const int*   labeling     = (const int*)d_in[2];
    const int*   logit_lgts   = (const int*)d_in[3];
    const int*   labeling_lgts= (const int*)d_in[4];
    float* out = (float*)d_out;
    char* ws = (char*)d_ws;

    size_t off = 0;
    f16*   wt     = (f16*)(ws + off);   off += (size_t)CP * DD * 2;        // 1.44 MB
    f16*   fn     = (f16*)(ws + off);   off += (size_t)TT * NN * DD * 2;   // 16.8 MB
    float* sumexp = (float*)(ws + off); off += (size_t)TT * NN * 4;        // 64 KB
    float* lp_lab = (float*)(ws + off); off += (size_t)NN * 31 * TT * 4;   // 2.0 MB
    double* part  = (double*)(ws + off); off += NN * 8;

    prep_kernel<<<PREP_WBLK + PREP_ZBLK + PREP_FBLK, 256, 0, stream>>>(
        W, feats, wt, fn, sumexp);
    gg_kernel<<<GG_BLK, 256, 0, stream>>>(fn, wt, labeling, sumexp, lp_lab);
    ctc_kernel<<<NN, 128, 0, stream>>>(lp_lab, labeling, logit_lgts,
                                       labeling_lgts, part);
    final_kernel<<<1, 1024, 0, stream>>>(sumexp, logit_lgts, part, out);

    (void)in_sizes; (void)n_in; (void)out_size; (void)ws_size;
}

// Round 14
// 149.489 us; speedup vs baseline: 1.2264x; 1.2094x over previous
//
#include <hip/hip_runtime.h>
#include <stdint.h>
#include <stddef.h>

// RadialCTC: cosine logits (norm_scale=32) -> log_softmax -> CTC(sum).
// Strategy: never materialize the (16384 x 1296) logits. GEMM (f16 MFMA)
// computes per-row sum(exp(logit)) fused in the epilogue; label log-probs via
// small f16 MFMA gather-GEMM; CTC alpha recursion one wave per sample.
// R9: linear f64 + pow2 renorm ctc. R11: XOR channel-slot LDS swizzle (gemm).
// R14: log2(sumexp) factored out (Msum). R15 FAILED: acquire-spin L2 storms.
// R18 (154.2): fused 2-step fwd chain: mega 54.9. R19 (153.2): XCD remap;
//   mega 54.4, VGPR 76. BEST fused. R20-R23: fwd/bwd split: verified but
//   regressed (VGPR/occupancy/serialized-staging).
// R24 (180.8): de-fused decomposition MEASURED the truth: gg ~44, standalone
//   uncontended ctc ~28-38us = 4-7x the VALU estimate -> the chain is LP
//   LOAD-LATENCY-BOUND (1-2 gi prefetch vs 300-900cyc L2/L3 latency), not
//   VALU-bound. R19-R23's "contention" was contended memory latency.
// R25 (this round): feed the chain from LDS. R19 skeleton (3 dispatches,
//   gemm verbatim, single fwd chain - no split needed at LDS rate). gc block
//   = producer-consumer pipeline: gather waves (R19 register-direct MFMA)
//   compute chunk c (31x128 lp) in regs -> B1 (chain done with c-1) ->
//   ds_write lps[31][132] (16B-aligned rows, 1-bank rotation) -> B2 ->
//   chain consumes chunk c from LDS (~120cyc, 1-gi prefetch covers) while
//   gather computes c+1. lp NEVER touches global (-2MB write, -2MB read).
//   8 matched barriers. Chain = R18-verified step2/renorm, bit-identical.

typedef _Float16 f16;
typedef _Float16 f16x8 __attribute__((ext_vector_type(8)));
typedef float f32x4 __attribute__((ext_vector_type(4)));
typedef __attribute__((address_space(1))) void* as1_void_ptr;
typedef __attribute__((address_space(3))) void* as3_void_ptr;

#define TT 512
#define NN 32
#define CC 1296
#define DD 512
#define SS 30
#define CP 1408   // C padded to 11*128 for GEMM tiling (pad rows are zero)
#define LL 61     // 2*S+1 CTC states
#define NORM_SCALE 32.0f
#define LOG2E 1.4426950408889634f
#define LN2   0.6931471805599453f
#define LPS_STRIDE 132   // floats/row: 528B = 16B-aligned, 33 words -> 1-bank rot

#define PREP_WBLK (CP / 16)            // 88 c-tiles of 16 (covers pad -> zeros)
#define PREP_ZBLK 16                   // 16 blocks zero sumexp
#define PREP_FBLK (TT * NN / 4)        // 4096 fnorm blocks (4 rows each)

#define GEMM_BLK ((TT * NN / 128) * (CP / 128))   // 128*11 = 1408
#define MEGA_GC  NN                                // 32 gather+ctc blocks
#define MEGA_BLK (MEGA_GC + GEMM_BLK)              // 1440

__device__ __forceinline__ float fexp2(float x) { return __builtin_amdgcn_exp2f(x); }
__device__ __forceinline__ float flog2(float x) { return __builtin_amdgcn_logf(x); }

// whole-wave shift-right-by-1 (lane s <- lane s-1; lane 0 gets 0): ctrl 0x138.
__device__ __forceinline__ double dpp_sr1_zero64(double x) {
    long long b = __double_as_longlong(x);
    int lo = (int)(b & 0xFFFFFFFFLL);
    int hi = (int)(b >> 32);
    int lo2 = __builtin_amdgcn_update_dpp(0, lo, 0x138, 0xF, 0xF, false);
    int hi2 = __builtin_amdgcn_update_dpp(0, hi, 0x138, 0xF, 0xF, false);
    return __longlong_as_double(((long long)hi2 << 32) |
                                (unsigned long long)(unsigned int)lo2);
}
// one level of DPP row-shr int max (identity 0; operands are >=0 hi-words)
template <int CTRL>
__device__ __forceinline__ int dpp_imax_level(int m) {
    int t = __builtin_amdgcn_update_dpp(0, m, CTRL, 0xF, 0xF, false);
    return m > t ? m : t;
}
// exact pow2 renorm of a nonneg f64 wave vector; accumulates exponent in Mi.
__device__ __forceinline__ void renorm_d(double& x, int& Mi) {
    int h = (int)(__double_as_longlong(x) >> 32);   // x>=0: hi-word monotone
    h = dpp_imax_level<0x111>(h);
    h = dpp_imax_level<0x112>(h);
    h = dpp_imax_level<0x114>(h);
    h = dpp_imax_level<0x118>(h);        // row max in lanes 15/31/47/63
    int r0 = __builtin_amdgcn_readlane(h, 15);
    int r1 = __builtin_amdgcn_readlane(h, 31);
    int r2 = __builtin_amdgcn_readlane(h, 47);
    int r3 = __builtin_amdgcn_readlane(h, 63);
    int mx = max(max(r0, r1), max(r2, r3));
    int e11 = mx >> 20;                  // biased 11-bit exponent
    double scale = __longlong_as_double((long long)(2046 - e11) << 52);
    x *= scale;
    Mi += e11 - 1023;
}

// ---- fused prep: W column-norm + transpose to f16 (atomic-free, per-block
//      column ownership), feats row-normalize -> f16, sumexp zeroing. ----
__global__ __launch_bounds__(256) void prep_kernel(const float* __restrict__ W,
                                                   const float* __restrict__ feats,
                                                   f16* __restrict__ wt,
                                                   f16* __restrict__ fn,
                                                   float* __restrict__ sumexp) {
    int bx = blockIdx.x, tid = threadIdx.x;
    if (bx < PREP_WBLK) {
        __shared__ float red[256];
        __shared__ float rqs[16];
        int c0 = bx * 16;
        int cl = tid & 15, dg = tid >> 4;
        int c = c0 + cl;
        float ss = 0.f;
        if (c < CC) {
            for (int d = dg; d < DD; d += 16) {
                float v = W[(size_t)d * CC + c];
                ss += v * v;
            }
        }
        red[tid] = ss;
        __syncthreads();
        if (tid < 16) {
            float s2 = 0.f;
            #pragma unroll
            for (int k = 0; k < 16; ++k) s2 += red[tid + 16 * k];
            rqs[tid] = rsqrtf(s2);
        }
        __syncthreads();
        int c_loc = tid >> 4, dl = tid & 15;
        int cc = c0 + c_loc;
        float rq = rqs[c_loc];
        #pragma unroll 4
        for (int it = 0; it < 32; ++it) {
            int d = dl + it * 16;
            float v = (cc < CC) ? W[(size_t)d * CC + cc] * rq : 0.f;
            wt[(size_t)cc * DD + d] = (f16)v;
        }
    } else if (bx < PREP_WBLK + PREP_ZBLK) {
        int zb = bx - PREP_WBLK;
        float4 z = {0.f, 0.f, 0.f, 0.f};
        ((float4*)sumexp)[zb * 256 + tid] = z;   // 16*256*16B = 64KB
    } else {
        int fb = bx - PREP_WBLK - PREP_ZBLK;
        int wv = (fb * 256 + tid) >> 6;  // row id, 0..16383
        int lane = tid & 63;
        const float4* src = (const float4*)(feats + (size_t)wv * DD) + lane * 2;
        float4 a = src[0], b = src[1];
        float ss = a.x*a.x + a.y*a.y + a.z*a.z + a.w*a.w
                 + b.x*b.x + b.y*b.y + b.z*b.z + b.w*b.w;
        #pragma unroll
        for (int off = 32; off; off >>= 1) ss += __shfl_xor(ss, off);
        float r = rsqrtf(ss);
        f16x8 o;
        o[0]=(f16)(a.x*r); o[1]=(f16)(a.y*r); o[2]=(f16)(a.z*r); o[3]=(f16)(a.w*r);
        o[4]=(f16)(b.x*r); o[5]=(f16)(b.y*r); o[6]=(f16)(b.z*r); o[7]=(f16)(b.w*r);
        *(f16x8*)(fn + (size_t)wv * DD + lane * 8) = o;
    }
}

// ---- gather pipeline (one wave, NT 16-row tiles starting at rbase within
//      each 128-t chunk): compute chunk c in regs (R19-verified register-
//      direct MFMA) -> B1 -> ds_write to lps -> B2; 4 chunks. ----
template <int NT>
__device__ __forceinline__ void gather_pipe(f16* sm,
                                            const f16* __restrict__ pb0,
                                            const f16* __restrict__ pb1,
                                            const f16* __restrict__ A,
                                            int n, int rbase, int lane) {
    int lm = lane & 15, hi = lane >> 4;
    float* lps = (float*)sm;
    #pragma unroll 1
    for (int c = 0; c < 4; ++c) {
        f32x4 acc[NT][2];
        #pragma unroll
        for (int i = 0; i < NT; ++i) {
            acc[i][0] = (f32x4){0.f, 0.f, 0.f, 0.f};
            acc[i][1] = (f32x4){0.f, 0.f, 0.f, 0.f};
        }
        const f16* pa0 = A + ((size_t)(c * 128 + rbase + lm) * NN + n) * DD + hi * 8;
        for (int kb = 0; kb < 16; ++kb) {
            f16x8 bf0 = *(const f16x8*)(pb0 + kb * 32);
            f16x8 bf1 = *(const f16x8*)(pb1 + kb * 32);
            #pragma unroll
            for (int i = 0; i < NT; ++i) {
                f16x8 af = *(const f16x8*)(pa0 + (size_t)(i * 16) * NN * DD + kb * 32);
                acc[i][0] = __builtin_amdgcn_mfma_f32_16x16x32_f16(af, bf0, acc[i][0], 0, 0, 0);
                acc[i][1] = __builtin_amdgcn_mfma_f32_16x16x32_f16(af, bf1, acc[i][1], 0, 0, 0);
            }
        }
        __syncthreads();     // B1: chain done consuming chunk c-1
        #pragma unroll
        for (int i = 0; i < NT; ++i) {
            #pragma unroll
            for (int jn = 0; jn < 2; ++jn) {
                int jc = jn * 16 + lm;
                if (jc >= 31) continue;
                float4 o;
                o.x = acc[i][jn][0] * (NORM_SCALE * LOG2E);
                o.y = acc[i][jn][1] * (NORM_SCALE * LOG2E);
                o.z = acc[i][jn][2] * (NORM_SCALE * LOG2E);
                o.w = acc[i][jn][3] * (NORM_SCALE * LOG2E);
                *(float4*)&lps[jc * LPS_STRIDE + rbase + i * 16 + hi * 4] = o;
            }
        }
        __syncthreads();     // B2: chunk c published
    }
}

// ---- mega (256-thr): blocks 0..31 = gc {w0 fwd chain fed from LDS, w1-3
//      gather pipeline NT=3/3/2}; blocks 32..1439 = gemm+sumexp (16KB LDS,
//      XOR swizzle, XCD-aware bm grouping) - byte-identical to R19. ----
__global__ __launch_bounds__(256) void mega_kernel(const f16* __restrict__ A,
                                                   const f16* __restrict__ B,
                                                   const int* __restrict__ labels,
                                                   const int* __restrict__ in_lens,
                                                   const int* __restrict__ lab_lens,
                                                   float* __restrict__ sumexp,
                                                   double* __restrict__ part) {
    __shared__ __align__(16) f16 sm[8192];   // 16KB: gemm tiles | gc lps[31][132]
    int bx = blockIdx.x;
    int tid = threadIdx.x;
    int w = tid >> 6, lane = tid & 63;
    int lm = lane & 15, hi = lane >> 4;
    int sw = (lm >> 1) & 3;                // fragment-read channel swizzle

    if (bx >= MEGA_GC) {
        // ================= GEMM section (identical since R19) ===============
        int j = bx - MEGA_GC;
        int x = j & 7, rr = j >> 3;            // XCD-aware: per-XCD bm range
        int bm = x * 16 + (rr & 15);
        int bn = rr >> 4;                      // [0,11)
        int wm = w >> 1, wn = w & 1;           // 2x2 wave grid -> 64x64 per wave
        f32x4 acc[4][4];
        f32x4 zero = {0.f, 0.f, 0.f, 0.f};
        #pragma unroll
        for (int i = 0; i < 4; ++i)
            #pragma unroll
            for (int jj = 0; jj < 4; ++jj) acc[i][jj] = zero;

        for (int kb = 0; kb < 16; ++kb) {      // K=512, BK=32 (one MFMA K-step)
            #pragma unroll
            for (int p = 0; p < 2; ++p) {
                int s = p * 256 + tid;
                int row = s >> 2;
                int ch = (s & 3) ^ ((row >> 1) & 3);   // swizzled source channel
                const f16* ga = A + (size_t)(bm * 128 + row) * DD + kb * 32 + ch * 8;
                const f16* gb = B + (size_t)(bn * 128 + row) * DD + kb * 32 + ch * 8;
                __builtin_amdgcn_global_load_lds((as1_void_ptr)ga,
                    (as3_void_ptr)&sm[(p * 256 + w * 64) * 8], 16, 0, 0);
                __builtin_amdgcn_global_load_lds((as1_void_ptr)gb,
                    (as3_void_ptr)&sm[4096 + (p * 256 + w * 64) * 8], 16, 0, 0);
            }
            __syncthreads();
            f16x8 af[4], bf[4];
            #pragma unroll
            for (int i = 0; i < 4; ++i)
                af[i] = *(const f16x8*)&sm[(wm * 64 + i * 16 + lm) * 32 + (hi ^ sw) * 8];
            #pragma unroll
            for (int jj = 0; jj < 4; ++jj)
                bf[jj] = *(const f16x8*)&sm[4096 + (wn * 64 + jj * 16 + lm) * 32 + (hi ^ sw) * 8];
            #pragma unroll
            for (int i = 0; i < 4; ++i)
                #pragma unroll
                for (int jj = 0; jj < 4; ++jj)
                    acc[i][jj] = __builtin_amdgcn_mfma_f32_16x16x32_f16(af[i], bf[jj], acc[i][jj], 0, 0, 0);
            __syncthreads();
        }
        #pragma unroll
        for (int i = 0; i < 4; ++i) {
            float rs[4] = {0.f, 0.f, 0.f, 0.f};
            #pragma unroll
            for (int jj = 0; jj < 4; ++jj) {
                int c = bn * 128 + wn * 64 + jj * 16 + lm;   // C/D: col = lane&15
                bool ok = (c < CC);
                #pragma unroll
                for (int r = 0; r < 4; ++r)
                    rs[r] += ok ? fexp2(acc[i][jj][r] * (NORM_SCALE * LOG2E)) : 0.f;
            }
            #pragma unroll
            for (int off = 1; off < 16; off <<= 1) {
                #pragma unroll
                for (int r = 0; r < 4; ++r) rs[r] += __shfl_xor(rs[r], off);
            }
            if (lm == 0) {
                int rowb = bm * 128 + wm * 64 + i * 16 + hi * 4;
                #pragma unroll
                for (int r = 0; r < 4; ++r) atomicAdd(&sumexp[rowb + r], rs[r]);
            }
        }
        return;
    }

    // ================= gather + ctc section (block n = bx) ==================
    int n = bx;
    if (w >= 1) {
        // gather pipeline waves: rows [0,48) / [48,96) / [96,128) per chunk
        __builtin_amdgcn_s_setprio(2);
        int cls0 = (lm == 0) ? 0 : labels[n * SS + lm - 1];       // j = lm
        int cls1 = (lm >= 15) ? 0 : labels[n * SS + lm + 15];     // j = 16+lm
        const f16* pb0 = B + (size_t)cls0 * DD + hi * 8;
        const f16* pb1 = B + (size_t)cls1 * DD + hi * 8;
        if (w < 3) gather_pipe<3>(sm, pb0, pb1, A, n, (w - 1) * 48, lane);
        else       gather_pipe<2>(sm, pb0, pb1, A, n, 96, lane);
        __builtin_amdgcn_s_setprio(0);
        return;
    }

    // wave 0: fwd chain (R18-verified math), fed from the LDS chunk buffer.
    int s = lane;            // 64 lanes; states 0..60 valid
    bool valid = s < LL;
    int ext = (valid && (s & 1)) ? labels[n * SS + (s >> 1)] : 0;
    int jmap = (valid && (s & 1)) ? ((s >> 1) + 1) : 0;   // state -> class slot
    int Tin = in_lens[n];    // wave-uniform; in [481,512]
    int ext2 = __shfl_up(ext, 2);
    double skipd = ((s >= 2) && valid && (ext != ext2)) ? 1.0 : 0.0;
    double sk1 = dpp_sr1_zero64(skipd);
    double sk2 = dpp_sr1_zero64(sk1);
    double kk2 = skipd * sk2;
    const float4* row4 = (const float4*)((float*)sm + jmap * LPS_STRIDE);

    double beta = 0.0;
    int Mif = 0;

    auto stepL = [&](float lp) {
        double P = (double)fexp2(lp);
        double b1 = dpp_sr1_zero64(beta);
        double b2 = dpp_sr1_zero64(b1);
        beta = (beta + b1 + b2 * skipd) * P;
    };
    auto step2 = [&](float lp1, float lp2) {
        double q  = (double)fexp2(lp1);
        double P2 = (double)fexp2(lp2);
        double q1 = dpp_sr1_zero64(q);
        double q2 = dpp_sr1_zero64(q1);
        double c1 = q + q1;
        double c2 = fma(skipd, q + q2, q1);
        double c3 = fma(sk1, q1, skipd * q2);
        double c4 = kk2 * q2;
        double b1 = dpp_sr1_zero64(beta);
        double b2 = dpp_sr1_zero64(b1);
        double b3 = dpp_sr1_zero64(b2);
        double b4 = dpp_sr1_zero64(b3);
        double u = fma(c1, b1, q * beta);
        double v2 = fma(c3, b3, c2 * b2);
        beta = (u + fma(c4, b4, v2)) * P2;
    };

    __builtin_amdgcn_s_setprio(3);
    int remaining = Tin - 1;   // steps t = 1..Tin-1
    int rnc = 0;
    #pragma unroll 1
    for (int c = 0; c < 4; ++c) {
        __syncthreads();       // B1 (match gather: it just finished compute(c))
        __syncthreads();       // B2: chunk c is in LDS
        if (c == 0) {
            float4 q0 = row4[0];
            beta = (s <= 1) ? (double)fexp2(q0.x) : 0.0;
            stepL(q0.y); stepL(q0.z); stepL(q0.w);   // t = 1..3
            renorm_d(beta, Mif);
            remaining -= 3;
            float4 cu = row4[1];
            for (int gi = 1; gi <= 31; ++gi) {       // t = 4..127
                float4 nx = row4[gi < 31 ? gi + 1 : 31];
                step2(cu.x, cu.y); step2(cu.z, cu.w);
                if (gi & 1) renorm_d(beta, Mif);
                cu = nx;
            }
            remaining -= 124;
        } else {
            float4 cu = row4[0];
            int gi = 0;
            while (remaining >= 4 && gi <= 31) {
                float4 nx = row4[gi < 31 ? gi + 1 : 31];
                step2(cu.x, cu.y); step2(cu.z, cu.w);
                rnc ^= 1;
                if (!rnc) renorm_d(beta, Mif);
                cu = nx; remaining -= 4; ++gi;
            }
            if (c == 3) {                            // tail 0..3 steps
                if (remaining > 0) stepL(cu.x);
                if (remaining > 1) stepL(cu.y);
                if (remaining > 2) stepL(cu.z);
            }
        }
    }
    renorm_d(beta, Mif);
    __builtin_amdgcn_s_setprio(0);

    int Ln = 2 * lab_lens[n] + 1;
    double last  = __shfl(beta, Ln - 1);
    double last2 = __shfl(beta, Ln - 2);
    double smv = last + last2;
    long long bb = __double_as_longlong(smv);
    int e = (int)(bb >> 52) - 1023;
    double mant = __longlong_as_double((bb & 0xFFFFFFFFFFFFFLL) | (1023LL << 52));
    if (s == 0)
        part[n] = (double)flog2((float)mant) + (double)(e + Mif);
}

// ---- final: Msum per n (f64, fixed order) + nll + deterministic sum ----
__global__ __launch_bounds__(1024) void final_kernel(const float* __restrict__ sumexp,
                                                     const int* __restrict__ in_lens,
                                                     const double* __restrict__ part,
                                                     float* __restrict__ out) {
    int tid = threadIdx.x;
    int v = tid >> 6, lane = tid & 63;     // 16 waves, 2 samples each
    __shared__ float nl[NN];
    #pragma unroll
    for (int k = 0; k < 2; ++k) {
        int n = v * 2 + k;
        int Tin = in_lens[n];
        double ms = 0.0;
        for (int t = lane; t < Tin; t += 64)
            ms += (double)flog2(sumexp[(size_t)t * NN + n]);
        #pragma unroll
        for (int off = 32; off; off >>= 1) ms += __shfl_xor(ms, off);
        if (lane == 0) nl[n] = (float)(-(part[n] - ms) * LN2);
    }
    __syncthreads();
    if (tid == 0) {
        float t = 0.f;
        for (int i = 0; i < NN; ++i) t += nl[i];
        out[0] = t;
    }
}

extern "C" void kernel_launch(void* const* d_in, const int* in_sizes, int n_in,
                              void* d_out, int out_size, void* d_ws, size_t ws_size,
                              hipStream_t stream) {
    const float* feats        = (const float*)d_in[0];
    const float* W            = (const float*)d_in[1];
    const int*   labeling     = (const int*)d_in[2];
    const int*   logit_lgts   = (const int*)d_in[3];
    const int*   labeling_lgts= (const int*)d_in[4];
    float* out = (float*)d_out;
    char* ws = (char*)d_ws;

    size_t off = 0;
    f16*   wt     = (f16*)(ws + off);   off += (size_t)CP * DD * 2;        // 1.44 MB
    f16*   fn     = (f16*)(ws + off);   off += (size_t)TT * NN * DD * 2;   // 16.8 MB
    float* sumexp = (float*)(ws + off); off += (size_t)TT * NN * 4;        // 64 KB
    double* part  = (double*)(ws + off); off += NN * 8;

    prep_kernel<<<PREP_WBLK + PREP_ZBLK + PREP_FBLK, 256, 0, stream>>>(
        W, feats, wt, fn, sumexp);
    mega_kernel<<<MEGA_BLK, 256, 0, stream>>>(fn, wt, labeling, logit_lgts,
                                              labeling_lgts, sumexp, part);
    final_kernel<<<1, 1024, 0, stream>>>(sumexp, logit_lgts, part, out);

    (void)in_sizes; (void)n_in; (void)out_size; (void)ws_size;
}

// Round 15
// 147.983 us; speedup vs baseline: 1.2389x; 1.0102x over previous
//
#include <hip/hip_runtime.h>
#include <stdint.h>
#include <stddef.h>

// RadialCTC: cosine logits (norm_scale=32) -> log_softmax -> CTC(sum).
// Strategy: never materialize the (16384 x 1296) logits. GEMM (f16 MFMA)
// computes per-row sum(exp(logit)) fused in the epilogue; label log-probs via
// small f16 MFMA gather-GEMM; CTC alpha recursion one wave per sample.
// R9: linear f64 + pow2 renorm ctc. R11: XOR channel-slot LDS swizzle (gemm).
// R14: log2(sumexp) factored out (Msum). R15 FAILED: acquire-spin L2 storms.
// R18/R19 (153.2): fused 2-step fwd chain + XCD remap; mega 54.4, VGPR 76.
// R24 (180.8): de-fused decomposition: standalone ctc 28-38us = lp
//   LOAD-LATENCY-BOUND (not VALU). R25 (149.5, NEW BEST): LDS-fed chain
//   (producer-consumer, lp never in global): mega 50.5, WRITE 7.6->5.6MB.
//   BUT VGPR 76->112: single-buffer forces acc[NT][2] live ACROSS B1
//   (compute -> barrier -> write) -> gemm 4 waves/SIMD instead of 6;
//   mega 50.5 is a reduced-occupancy gemm.
// R26 (this round): DOUBLE-BUFFER the lp LDS (2 x 31x132 f32 = 32.7KB).
//   Gather: compute chunk c -> write IMMEDIATELY to buf[c&1] (R19-style
//   short acc live range) -> one barrier/chunk. Chain consumes buf[c&1]
//   between barriers while gather computes c+1 into the other buffer
//   (hazard-free by barrier order). Barriers 8->4. LDS 32.7KB caps gemm at
//   5 blocks/CU (20 waves) -- beats the VGPR-112 cap (16 waves). Chain
//   math / renorm cadence / MFMA order byte-identical to R25.

typedef _Float16 f16;
typedef _Float16 f16x8 __attribute__((ext_vector_type(8)));
typedef float f32x4 __attribute__((ext_vector_type(4)));
typedef __attribute__((address_space(1))) void* as1_void_ptr;
typedef __attribute__((address_space(3))) void* as3_void_ptr;

#define TT 512
#define NN 32
#define CC 1296
#define DD 512
#define SS 30
#define CP 1408   // C padded to 11*128 for GEMM tiling (pad rows are zero)
#define LL 61     // 2*S+1 CTC states
#define NORM_SCALE 32.0f
#define LOG2E 1.4426950408889634f
#define LN2   0.6931471805599453f
#define LPS_STRIDE 132   // floats/row: 528B = 16B-aligned, 4-bank rotation

#define PREP_WBLK (CP / 16)            // 88 c-tiles of 16 (covers pad -> zeros)
#define PREP_ZBLK 16                   // 16 blocks zero sumexp
#define PREP_FBLK (TT * NN / 4)        // 4096 fnorm blocks (4 rows each)

#define GEMM_BLK ((TT * NN / 128) * (CP / 128))   // 128*11 = 1408
#define MEGA_GC  NN                                // 32 gather+ctc blocks
#define MEGA_BLK (MEGA_GC + GEMM_BLK)              // 1440

__device__ __forceinline__ float fexp2(float x) { return __builtin_amdgcn_exp2f(x); }
__device__ __forceinline__ float flog2(float x) { return __builtin_amdgcn_logf(x); }

// whole-wave shift-right-by-1 (lane s <- lane s-1; lane 0 gets 0): ctrl 0x138.
__device__ __forceinline__ double dpp_sr1_zero64(double x) {
    long long b = __double_as_longlong(x);
    int lo = (int)(b & 0xFFFFFFFFLL);
    int hi = (int)(b >> 32);
    int lo2 = __builtin_amdgcn_update_dpp(0, lo, 0x138, 0xF, 0xF, false);
    int hi2 = __builtin_amdgcn_update_dpp(0, hi, 0x138, 0xF, 0xF, false);
    return __longlong_as_double(((long long)hi2 << 32) |
                                (unsigned long long)(unsigned int)lo2);
}
// one level of DPP row-shr int max (identity 0; operands are >=0 hi-words)
template <int CTRL>
__device__ __forceinline__ int dpp_imax_level(int m) {
    int t = __builtin_amdgcn_update_dpp(0, m, CTRL, 0xF, 0xF, false);
    return m > t ? m : t;
}
// exact pow2 renorm of a nonneg f64 wave vector; accumulates exponent in Mi.
__device__ __forceinline__ void renorm_d(double& x, int& Mi) {
    int h = (int)(__double_as_longlong(x) >> 32);   // x>=0: hi-word monotone
    h = dpp_imax_level<0x111>(h);
    h = dpp_imax_level<0x112>(h);
    h = dpp_imax_level<0x114>(h);
    h = dpp_imax_level<0x118>(h);        // row max in lanes 15/31/47/63
    int r0 = __builtin_amdgcn_readlane(h, 15);
    int r1 = __builtin_amdgcn_readlane(h, 31);
    int r2 = __builtin_amdgcn_readlane(h, 47);
    int r3 = __builtin_amdgcn_readlane(h, 63);
    int mx = max(max(r0, r1), max(r2, r3));
    int e11 = mx >> 20;                  // biased 11-bit exponent
    double scale = __longlong_as_double((long long)(2046 - e11) << 52);
    x *= scale;
    Mi += e11 - 1023;
}

// ---- fused prep: W column-norm + transpose to f16 (atomic-free, per-block
//      column ownership), feats row-normalize -> f16, sumexp zeroing. ----
__global__ __launch_bounds__(256) void prep_kernel(const float* __restrict__ W,
                                                   const float* __restrict__ feats,
                                                   f16* __restrict__ wt,
                                                   f16* __restrict__ fn,
                                                   float* __restrict__ sumexp) {
    int bx = blockIdx.x, tid = threadIdx.x;
    if (bx < PREP_WBLK) {
        __shared__ float red[256];
        __shared__ float rqs[16];
        int c0 = bx * 16;
        int cl = tid & 15, dg = tid >> 4;
        int c = c0 + cl;
        float ss = 0.f;
        if (c < CC) {
            for (int d = dg; d < DD; d += 16) {
                float v = W[(size_t)d * CC + c];
                ss += v * v;
            }
        }
        red[tid] = ss;
        __syncthreads();
        if (tid < 16) {
            float s2 = 0.f;
            #pragma unroll
            for (int k = 0; k < 16; ++k) s2 += red[tid + 16 * k];
            rqs[tid] = rsqrtf(s2);
        }
        __syncthreads();
        int c_loc = tid >> 4, dl = tid & 15;
        int cc = c0 + c_loc;
        float rq = rqs[c_loc];
        #pragma unroll 4
        for (int it = 0; it < 32; ++it) {
            int d = dl + it * 16;
            float v = (cc < CC) ? W[(size_t)d * CC + cc] * rq : 0.f;
            wt[(size_t)cc * DD + d] = (f16)v;
        }
    } else if (bx < PREP_WBLK + PREP_ZBLK) {
        int zb = bx - PREP_WBLK;
        float4 z = {0.f, 0.f, 0.f, 0.f};
        ((float4*)sumexp)[zb * 256 + tid] = z;   // 16*256*16B = 64KB
    } else {
        int fb = bx - PREP_WBLK - PREP_ZBLK;
        int wv = (fb * 256 + tid) >> 6;  // row id, 0..16383
        int lane = tid & 63;
        const float4* src = (const float4*)(feats + (size_t)wv * DD) + lane * 2;
        float4 a = src[0], b = src[1];
        float ss = a.x*a.x + a.y*a.y + a.z*a.z + a.w*a.w
                 + b.x*b.x + b.y*b.y + b.z*b.z + b.w*b.w;
        #pragma unroll
        for (int off = 32; off; off >>= 1) ss += __shfl_xor(ss, off);
        float r = rsqrtf(ss);
        f16x8 o;
        o[0]=(f16)(a.x*r); o[1]=(f16)(a.y*r); o[2]=(f16)(a.z*r); o[3]=(f16)(a.w*r);
        o[4]=(f16)(b.x*r); o[5]=(f16)(b.y*r); o[6]=(f16)(b.z*r); o[7]=(f16)(b.w*r);
        *(f16x8*)(fn + (size_t)wv * DD + lane * 8) = o;
    }
}

// ---- gather pipeline (one wave, NT 16-row tiles at rbase in each 128-t
//      chunk): compute chunk c in regs (R19-verified register-direct MFMA),
//      write IMMEDIATELY to buf[c&1], then one barrier per chunk. ----
template <int NT>
__device__ __forceinline__ void gather_pipe(float* lps0, float* lps1,
                                            const f16* __restrict__ pb0,
                                            const f16* __restrict__ pb1,
                                            const f16* __restrict__ A,
                                            int n, int rbase, int lane) {
    int lm = lane & 15, hi = lane >> 4;
    #pragma unroll 1
    for (int c = 0; c < 4; ++c) {
        f32x4 acc[NT][2];
        #pragma unroll
        for (int i = 0; i < NT; ++i) {
            acc[i][0] = (f32x4){0.f, 0.f, 0.f, 0.f};
            acc[i][1] = (f32x4){0.f, 0.f, 0.f, 0.f};
        }
        const f16* pa0 = A + ((size_t)(c * 128 + rbase + lm) * NN + n) * DD + hi * 8;
        for (int kb = 0; kb < 16; ++kb) {
            f16x8 bf0 = *(const f16x8*)(pb0 + kb * 32);
            f16x8 bf1 = *(const f16x8*)(pb1 + kb * 32);
            #pragma unroll
            for (int i = 0; i < NT; ++i) {
                f16x8 af = *(const f16x8*)(pa0 + (size_t)(i * 16) * NN * DD + kb * 32);
                acc[i][0] = __builtin_amdgcn_mfma_f32_16x16x32_f16(af, bf0, acc[i][0], 0, 0, 0);
                acc[i][1] = __builtin_amdgcn_mfma_f32_16x16x32_f16(af, bf1, acc[i][1], 0, 0, 0);
            }
        }
        float* lps = (c & 1) ? lps1 : lps0;
        #pragma unroll
        for (int i = 0; i < NT; ++i) {
            #pragma unroll
            for (int jn = 0; jn < 2; ++jn) {
                int jc = jn * 16 + lm;
                if (jc >= 31) continue;
                float4 o;
                o.x = acc[i][jn][0] * (NORM_SCALE * LOG2E);
                o.y = acc[i][jn][1] * (NORM_SCALE * LOG2E);
                o.z = acc[i][jn][2] * (NORM_SCALE * LOG2E);
                o.w = acc[i][jn][3] * (NORM_SCALE * LOG2E);
                *(float4*)&lps[jc * LPS_STRIDE + rbase + i * 16 + hi * 4] = o;
            }
        }
        __syncthreads();     // B(c): chunk c published; chain done with c-2's buf
    }
}

// ---- mega (256-thr): blocks 0..31 = gc {w0 fwd chain fed from double-
//      buffered LDS, w1-3 gather pipeline NT=3/3/2}; blocks 32..1439 =
//      gemm+sumexp (16KB of the 32.7KB LDS, XOR swizzle, XCD-aware bm). ----
__global__ __launch_bounds__(256) void mega_kernel(const f16* __restrict__ A,
                                                   const f16* __restrict__ B,
                                                   const int* __restrict__ labels,
                                                   const int* __restrict__ in_lens,
                                                   const int* __restrict__ lab_lens,
                                                   float* __restrict__ sumexp,
                                                   double* __restrict__ part) {
    __shared__ __align__(16) float smf[2 * 31 * LPS_STRIDE];   // 32,736 B
    f16* sm = (f16*)smf;                   // gemm view (uses first 16 KB)
    float* lps0 = smf;
    float* lps1 = smf + 31 * LPS_STRIDE;
    int bx = blockIdx.x;
    int tid = threadIdx.x;
    int w = tid >> 6, lane = tid & 63;
    int lm = lane & 15, hi = lane >> 4;
    int sw = (lm >> 1) & 3;                // fragment-read channel swizzle

    if (bx >= MEGA_GC) {
        // ================= GEMM section (identical since R19) ===============
        int j = bx - MEGA_GC;
        int x = j & 7, rr = j >> 3;            // XCD-aware: per-XCD bm range
        int bm = x * 16 + (rr & 15);
        int bn = rr >> 4;                      // [0,11)
        int wm = w >> 1, wn = w & 1;           // 2x2 wave grid -> 64x64 per wave
        f32x4 acc[4][4];
        f32x4 zero = {0.f, 0.f, 0.f, 0.f};
        #pragma unroll
        for (int i = 0; i < 4; ++i)
            #pragma unroll
            for (int jj = 0; jj < 4; ++jj) acc[i][jj] = zero;

        for (int kb = 0; kb < 16; ++kb) {      // K=512, BK=32 (one MFMA K-step)
            #pragma unroll
            for (int p = 0; p < 2; ++p) {
                int s = p * 256 + tid;
                int row = s >> 2;
                int ch = (s & 3) ^ ((row >> 1) & 3);   // swizzled source channel
                const f16* ga = A + (size_t)(bm * 128 + row) * DD + kb * 32 + ch * 8;
                const f16* gb = B + (size_t)(bn * 128 + row) * DD + kb * 32 + ch * 8;
                __builtin_amdgcn_global_load_lds((as1_void_ptr)ga,
                    (as3_void_ptr)&sm[(p * 256 + w * 64) * 8], 16, 0, 0);
                __builtin_amdgcn_global_load_lds((as1_void_ptr)gb,
                    (as3_void_ptr)&sm[4096 + (p * 256 + w * 64) * 8], 16, 0, 0);
            }
            __syncthreads();
            f16x8 af[4], bf[4];
            #pragma unroll
            for (int i = 0; i < 4; ++i)
                af[i] = *(const f16x8*)&sm[(wm * 64 + i * 16 + lm) * 32 + (hi ^ sw) * 8];
            #pragma unroll
            for (int jj = 0; jj < 4; ++jj)
                bf[jj] = *(const f16x8*)&sm[4096 + (wn * 64 + jj * 16 + lm) * 32 + (hi ^ sw) * 8];
            #pragma unroll
            for (int i = 0; i < 4; ++i)
                #pragma unroll
                for (int jj = 0; jj < 4; ++jj)
                    acc[i][jj] = __builtin_amdgcn_mfma_f32_16x16x32_f16(af[i], bf[jj], acc[i][jj], 0, 0, 0);
            __syncthreads();
        }
        #pragma unroll
        for (int i = 0; i < 4; ++i) {
            float rs[4] = {0.f, 0.f, 0.f, 0.f};
            #pragma unroll
            for (int jj = 0; jj < 4; ++jj) {
                int c = bn * 128 + wn * 64 + jj * 16 + lm;   // C/D: col = lane&15
                bool ok = (c < CC);
                #pragma unroll
                for (int r = 0; r < 4; ++r)
                    rs[r] += ok ? fexp2(acc[i][jj][r] * (NORM_SCALE * LOG2E)) : 0.f;
            }
            #pragma unroll
            for (int off = 1; off < 16; off <<= 1) {
                #pragma unroll
                for (int r = 0; r < 4; ++r) rs[r] += __shfl_xor(rs[r], off);
            }
            if (lm == 0) {
                int rowb = bm * 128 + wm * 64 + i * 16 + hi * 4;
                #pragma unroll
                for (int r = 0; r < 4; ++r) atomicAdd(&sumexp[rowb + r], rs[r]);
            }
        }
        return;
    }

    // ================= gather + ctc section (block n = bx) ==================
    int n = bx;
    if (w >= 1) {
        // gather pipeline waves: rows [0,48) / [48,96) / [96,128) per chunk
        __builtin_amdgcn_s_setprio(2);
        int cls0 = (lm == 0) ? 0 : labels[n * SS + lm - 1];       // j = lm
        int cls1 = (lm >= 15) ? 0 : labels[n * SS + lm + 15];     // j = 16+lm
        const f16* pb0 = B + (size_t)cls0 * DD + hi * 8;
        const f16* pb1 = B + (size_t)cls1 * DD + hi * 8;
        if (w < 3) gather_pipe<3>(lps0, lps1, pb0, pb1, A, n, (w - 1) * 48, lane);
        else       gather_pipe<2>(lps0, lps1, pb0, pb1, A, n, 96, lane);
        __builtin_amdgcn_s_setprio(0);
        return;
    }

    // wave 0: fwd chain (R18-verified math), fed from double-buffered LDS.
    int s = lane;            // 64 lanes; states 0..60 valid
    bool valid = s < LL;
    int ext = (valid && (s & 1)) ? labels[n * SS + (s >> 1)] : 0;
    int jmap = (valid && (s & 1)) ? ((s >> 1) + 1) : 0;   // state -> class slot
    int Tin = in_lens[n];    // wave-uniform; in [481,512]
    int ext2 = __shfl_up(ext, 2);
    double skipd = ((s >= 2) && valid && (ext != ext2)) ? 1.0 : 0.0;
    double sk1 = dpp_sr1_zero64(skipd);
    double sk2 = dpp_sr1_zero64(sk1);
    double kk2 = skipd * sk2;

    double beta = 0.0;
    int Mif = 0;

    auto stepL = [&](float lp) {
        double P = (double)fexp2(lp);
        double b1 = dpp_sr1_zero64(beta);
        double b2 = dpp_sr1_zero64(b1);
        beta = (beta + b1 + b2 * skipd) * P;
    };
    auto step2 = [&](float lp1, float lp2) {
        double q  = (double)fexp2(lp1);
        double P2 = (double)fexp2(lp2);
        double q1 = dpp_sr1_zero64(q);
        double q2 = dpp_sr1_zero64(q1);
        double c1 = q + q1;
        double c2 = fma(skipd, q + q2, q1);
        double c3 = fma(sk1, q1, skipd * q2);
        double c4 = kk2 * q2;
        double b1 = dpp_sr1_zero64(beta);
        double b2 = dpp_sr1_zero64(b1);
        double b3 = dpp_sr1_zero64(b2);
        double b4 = dpp_sr1_zero64(b3);
        double u = fma(c1, b1, q * beta);
        double v2 = fma(c3, b3, c2 * b2);
        beta = (u + fma(c4, b4, v2)) * P2;
    };

    __builtin_amdgcn_s_setprio(3);
    int remaining = Tin - 1;   // steps t = 1..Tin-1
    int rnc = 0;
    #pragma unroll 1
    for (int c = 0; c < 4; ++c) {
        __syncthreads();       // B(c): chunk c published in buf[c&1]
        const float4* row4 = (const float4*)(((c & 1) ? lps1 : lps0)
                                             + jmap * LPS_STRIDE);
        if (c == 0) {
            float4 q0 = row4[0];
            beta = (s <= 1) ? (double)fexp2(q0.x) : 0.0;
            stepL(q0.y); stepL(q0.z); stepL(q0.w);   // t = 1..3
            renorm_d(beta, Mif);
            remaining -= 3;
            float4 cu = row4[1];
            for (int gi = 1; gi <= 31; ++gi) {       // t = 4..127
                float4 nx = row4[gi < 31 ? gi + 1 : 31];
                step2(cu.x, cu.y); step2(cu.z, cu.w);
                if (gi & 1) renorm_d(beta, Mif);
                cu = nx;
            }
            remaining -= 124;
        } else {
            float4 cu = row4[0];
            int gi = 0;
            while (remaining >= 4 && gi <= 31) {
                float4 nx = row4[gi < 31 ? gi + 1 : 31];
                step2(cu.x, cu.y); step2(cu.z, cu.w);
                rnc ^= 1;
                if (!rnc) renorm_d(beta, Mif);
                cu = nx; remaining -= 4; ++gi;
            }
            if (c == 3) {                            // tail 0..3 steps
                if (remaining > 0) stepL(cu.x);
                if (remaining > 1) stepL(cu.y);
                if (remaining > 2) stepL(cu.z);
            }
        }
    }
    renorm_d(beta, Mif);
    __builtin_amdgcn_s_setprio(0);

    int Ln = 2 * lab_lens[n] + 1;
    double last  = __shfl(beta, Ln - 1);
    double last2 = __shfl(beta, Ln - 2);
    double smv = last + last2;
    long long bb = __double_as_longlong(smv);
    int e = (int)(bb >> 52) - 1023;
    double mant = __longlong_as_double((bb & 0xFFFFFFFFFFFFFLL) | (1023LL << 52));
    if (s == 0)
        part[n] = (double)flog2((float)mant) + (double)(e + Mif);
}

// ---- final: Msum per n (f64, fixed order) + nll + deterministic sum ----
__global__ __launch_bounds__(1024) void final_kernel(const float* __restrict__ sumexp,
                                                     const int* __restrict__ in_lens,
                                                     const double* __restrict__ part,
                                                     float* __restrict__ out) {
    int tid = threadIdx.x;
    int v = tid >> 6, lane = tid & 63;     // 16 waves, 2 samples each
    __shared__ float nl[NN];
    #pragma unroll
    for (int k = 0; k < 2; ++k) {
        int n = v * 2 + k;
        int Tin = in_lens[n];
        double ms = 0.0;
        for (int t = lane; t < Tin; t += 64)
            ms += (double)flog2(sumexp[(size_t)t * NN + n]);
        #pragma unroll
        for (int off = 32; off; off >>= 1) ms += __shfl_xor(ms, off);
        if (lane == 0) nl[n] = (float)(-(part[n] - ms) * LN2);
    }
    __syncthreads();
    if (tid == 0) {
        float t = 0.f;
        for (int i = 0; i < NN; ++i) t += nl[i];
        out[0] = t;
    }
}

extern "C" void kernel_launch(void* const* d_in, const int* in_sizes, int n_in,
                              void* d_out, int out_size, void* d_ws, size_t ws_size,
                              hipStream_t stream) {
    const float* feats        = (const float*)d_in[0];
    const float* W            = (const float*)d_in[1];
    const int*   labeling     = (const int*)d_in[2];
    const int*   logit_lgts   = (const int*)d_in[3];
    const int*   labeling_lgts= (const int*)d_in[4];
    float* out = (float*)d_out;
    char* ws = (char*)d_ws;

    size_t off = 0;
    f16*   wt     = (f16*)(ws + off);   off += (size_t)CP * DD * 2;        // 1.44 MB
    f16*   fn     = (f16*)(ws + off);   off += (size_t)TT * NN * DD * 2;   // 16.8 MB
    float* sumexp = (float*)(ws + off); off += (size_t)TT * NN * 4;        // 64 KB
    double* part  = (double*)(ws + off); off += NN * 8;

    prep_kernel<<<PREP_WBLK + PREP_ZBLK + PREP_FBLK, 256, 0, stream>>>(
        W, feats, wt, fn, sumexp);
    mega_kernel<<<MEGA_BLK, 256, 0, stream>>>(fn, wt, labeling, logit_lgts,
                                              labeling_lgts, sumexp, part);
    final_kernel<<<1, 1024, 0, stream>>>(sumexp, logit_lgts, part, out);

    (void)in_sizes; (void)n_in; (void)out_size; (void)ws_size;
}